// Round 9
// baseline (34.827 us; speedup 1.0000x reference)
//
#include <hip/hip_runtime.h>
#include <math.h>

// WindAdjacency: A[b,i,j] = mask*exp(align - D/R)*speed, row-normalized.
// B=8, N=2048. Round-9: minimal per-thread chain. 16384 blocks (one per (b,i),
// R6's XCD batch-adjacent mapping) x 512 threads, ONE f32x4 per thread:
//   - per-thread: 2 loads, 4 elements, 1 store -> shortest dependency chain
//   - ~32-40 VGPR -> 32 waves/CU (max occupancy)
//   - keeps R6's proven L2 win: row i's 8 batch-blocks adjacent on one XCD

#define NN 2048
#define BB 8

typedef float f32x4 __attribute__((ext_vector_type(4)));

__global__ __launch_bounds__(512) void wind_adj_kernel(
    const float* __restrict__ wind_feats,  // [B,N,2]
    const float* __restrict__ D,           // [N,N]
    const float* __restrict__ Theta,       // [N,N]
    float* __restrict__ out)               // [B,N,N]
{
    constexpr float PI_F     = 3.14159265358979323846f;
    constexpr float TWO_PI_F = 6.28318530717958647692f;
    constexpr float CONE_F   = 0.78539816339744830962f;  // f32(pi/4)
    constexpr float R_INV    = 1.0f / 150.0f;
    constexpr float EPS      = 1e-8f;

    // R6 mapping: p -> (xcd x, batch b, row i); p%8 = XCD under round-robin.
    // Row i's 8 batch-blocks sit at adjacent slots on one XCD -> L2 re-reads.
    const int p = blockIdx.x;
    const int x = p & 7;
    const int q = p >> 3;
    const int b = q & 7;
    const int i = (x << 8) | (q >> 3);

    const int tid = threadIdx.x;  // 0..511, one f32x4 (4 j's)

    const f32x4 d4 = reinterpret_cast<const f32x4*>(D     + (size_t)i * NN)[tid];
    const f32x4 t4 = reinterpret_cast<const f32x4*>(Theta + (size_t)i * NN)[tid];

    const float speed = wind_feats[((size_t)b * NN + i) * 2 + 0];
    float wind_to     = wind_feats[((size_t)b * NN + i) * 2 + 1] + PI_F;
    if (wind_to >= TWO_PI_F) wind_to -= TWO_PI_F;   // dir in [0,1): mod is identity

    float vals[4];
    float psum = 0.0f;
    #pragma unroll
    for (int e = 0; e < 4; ++e) {
        const int j = tid * 4 + e;
        // exact f32 replication of ref: ang = ((Theta - wind_to) + pi) mod 2pi - pi
        float t = t4[e] - wind_to + PI_F;        // in (-1, 2pi]
        t = (t < 0.0f) ? (t + TWO_PI_F) : t;     // == np.mod for this range
        float ang = t - PI_F;
        float align = fmaxf(__cosf(ang), 0.0f);
        float v = __expf(__builtin_fmaf(d4[e], -R_INV, align));  // exp(align - D/R)
        v = (fabsf(ang) <= CONE_F) ? v : 0.0f;   // cone mask, bit-exact compare
        v = (j == i) ? 0.0f : v;                 // no self loop
        vals[e] = v;
        psum += v;
    }

    // wave butterfly then LDS across the 8 waves
    float s = psum;
    #pragma unroll
    for (int off = 32; off > 0; off >>= 1) s += __shfl_down(s, off);
    __shared__ float wsum[8];
    const int lane = tid & 63, wid = tid >> 6;
    if (lane == 0) wsum[wid] = s;
    __syncthreads();
    float total = 0.0f;
    #pragma unroll
    for (int w = 0; w < 8; ++w) total += wsum[w];

    // A = (v*speed) / (sum(v)*speed + eps)
    const float scale = speed / __builtin_fmaf(total, speed, EPS);

    f32x4 o;
    o[0] = vals[0] * scale;
    o[1] = vals[1] * scale;
    o[2] = vals[2] * scale;
    o[3] = vals[3] * scale;
    reinterpret_cast<f32x4*>(out + ((size_t)b * NN + i) * NN)[tid] = o;
}

extern "C" void kernel_launch(void* const* d_in, const int* in_sizes, int n_in,
                              void* d_out, int out_size, void* d_ws, size_t ws_size,
                              hipStream_t stream) {
    const float* wind_feats = (const float*)d_in[0];  // [8,2048,2]
    const float* D_ij       = (const float*)d_in[1];  // [2048,2048]
    const float* Theta_ij   = (const float*)d_in[2];  // [2048,2048]
    float* out = (float*)d_out;                       // [8,2048,2048]

    dim3 grid(BB * NN);   // 16384 blocks: p -> (xcd, batch, row)
    dim3 block(512);
    wind_adj_kernel<<<grid, block, 0, stream>>>(wind_feats, D_ij, Theta_ij, out);
}

// Round 10
// 30.995 us; speedup vs baseline: 1.1236x; 1.1236x over previous
//
#include <hip/hip_runtime.h>
#include <math.h>

// WindAdjacency: A[b,i,j] = mask*exp(align - D/R)*speed, row-normalized.
// B=8, N=2048. Round-10: REVERT to round-6 (best of 6 structural variants).
// One block per (b,i) pair, 256 threads, 2 float4/thread.
//   - XCD-aware mapping: p%8 = XCD slot; row i's 8 batch-blocks land on the
//     SAME XCD at ADJACENT dispatch slots -> 7 of 8 D/Theta row re-reads are
//     L2 hits (R7 proved this is worth ~2x: linear mapping = 58.8us)
//   - 256-thr blocks beat 512 in every A/B (R2/R5, R6/R9): finer dispatch,
//     narrower barrier
//   - structural sweep (R2,R5,R6,R7,R8,R9) brackets this as optimum:
//     31.1us = 86% of the 6.29TB/s measured copy ceiling on 167.8MB traffic

#define NN 2048
#define BB 8

typedef float f32x4 __attribute__((ext_vector_type(4)));

__global__ __launch_bounds__(256) void wind_adj_kernel(
    const float* __restrict__ wind_feats,  // [B,N,2]
    const float* __restrict__ D,           // [N,N]
    const float* __restrict__ Theta,       // [N,N]
    float* __restrict__ out)               // [B,N,N]
{
    constexpr float PI_F     = 3.14159265358979323846f;
    constexpr float TWO_PI_F = 6.28318530717958647692f;
    constexpr float CONE_F   = 0.78539816339744830962f;  // f32(pi/4)
    constexpr float R_INV    = 1.0f / 150.0f;
    constexpr float EPS      = 1e-8f;

    // physical block p -> (xcd slot x, batch b, row i); p%8 selects XCD under
    // round-robin dispatch. XCD x owns rows [x*256, (x+1)*256); the 8 batches
    // of a row are adjacent in dispatch order on that XCD.
    const int p = blockIdx.x;
    const int x = p & 7;
    const int q = p >> 3;
    const int b = q & 7;
    const int i = (x << 8) | (q >> 3);

    const int tid = threadIdx.x;  // 0..255, two float4 (8 j's) per thread

    const f32x4* __restrict__ Drow = reinterpret_cast<const f32x4*>(D     + (size_t)i * NN);
    const f32x4* __restrict__ Trow = reinterpret_cast<const f32x4*>(Theta + (size_t)i * NN);
    const f32x4 d4a = Drow[tid];
    const f32x4 t4a = Trow[tid];
    const f32x4 d4b = Drow[256 + tid];
    const f32x4 t4b = Trow[256 + tid];

    const float speed = wind_feats[((size_t)b * NN + i) * 2 + 0];
    float wind_to     = wind_feats[((size_t)b * NN + i) * 2 + 1] + PI_F;
    if (wind_to >= TWO_PI_F) wind_to -= TWO_PI_F;   // dir in [0,1): mod is identity

    float vals[2][4];
    float psum = 0.0f;

    #pragma unroll
    for (int h = 0; h < 2; ++h) {
        const f32x4 d4 = h ? d4b : d4a;
        const f32x4 t4 = h ? t4b : t4a;
        #pragma unroll
        for (int e = 0; e < 4; ++e) {
            const int j = (h * 256 + tid) * 4 + e;
            // exact f32 replication of ref: ang = ((Theta - wind_to) + pi) mod 2pi - pi
            float t = t4[e] - wind_to + PI_F;        // in (-1, 2pi]
            t = (t < 0.0f) ? (t + TWO_PI_F) : t;     // == np.mod for this range
            float ang = t - PI_F;
            float align = fmaxf(__cosf(ang), 0.0f);
            float v = __expf(__builtin_fmaf(d4[e], -R_INV, align));  // exp(align - D/R)
            v = (fabsf(ang) <= CONE_F) ? v : 0.0f;   // cone mask, bit-exact compare
            v = (j == i) ? 0.0f : v;                 // no self loop
            vals[h][e] = v;
            psum += v;
        }
    }

    // block reduction: wave butterfly then LDS across the 4 waves
    float s = psum;
    #pragma unroll
    for (int off = 32; off > 0; off >>= 1) s += __shfl_down(s, off);
    __shared__ float wsum[4];
    const int lane = tid & 63, wid = tid >> 6;
    if (lane == 0) wsum[wid] = s;
    __syncthreads();
    const float total = wsum[0] + wsum[1] + wsum[2] + wsum[3];

    // A = (v*speed) / (sum(v)*speed + eps)
    const float scale = speed / __builtin_fmaf(total, speed, EPS);

    f32x4* __restrict__ Orow = reinterpret_cast<f32x4*>(out + ((size_t)b * NN + i) * NN);
    #pragma unroll
    for (int h = 0; h < 2; ++h) {
        f32x4 o;
        o[0] = vals[h][0] * scale;
        o[1] = vals[h][1] * scale;
        o[2] = vals[h][2] * scale;
        o[3] = vals[h][3] * scale;
        Orow[h * 256 + tid] = o;
    }
}

extern "C" void kernel_launch(void* const* d_in, const int* in_sizes, int n_in,
                              void* d_out, int out_size, void* d_ws, size_t ws_size,
                              hipStream_t stream) {
    const float* wind_feats = (const float*)d_in[0];  // [8,2048,2]
    const float* D_ij       = (const float*)d_in[1];  // [2048,2048]
    const float* Theta_ij   = (const float*)d_in[2];  // [2048,2048]
    float* out = (float*)d_out;                       // [8,2048,2048]

    dim3 grid(BB * NN);   // 16384 blocks: p -> (xcd, batch, row)
    dim3 block(256);
    wind_adj_kernel<<<grid, block, 0, stream>>>(wind_feats, D_ij, Theta_ij, out);
}